// Round 23
// baseline (153.050 us; speedup 1.0000x reference)
//
#include <hip/hip_runtime.h>
#include <hip/hip_cooperative_groups.h>
#include <math.h>

namespace cg = cooperative_groups;

constexpr int D = 128;
constexpr int BCAP = 4096;                 // per-bucket capacity (max ~3400)

typedef __attribute__((ext_vector_type(8))) short short8;
typedef __attribute__((ext_vector_type(4))) float f32x4;
typedef unsigned short ushort_t;
typedef unsigned int uint_t;

__device__ inline ushort_t f2b(float x) {          // fp32 -> bf16 RNE
    uint_t u = __float_as_uint(x);
    uint_t r = u + 0x7fffu + ((u >> 16) & 1u);
    return (ushort_t)(r >> 16);
}
__device__ inline float b2f(ushort_t b) { return __uint_as_float(((uint_t)b) << 16); }

__device__ inline float sigm(float x) { return 1.f / (1.f + __expf(-x)); }
__device__ inline float tanh_(float x) {
    float t = __expf(-2.f * fabsf(x));
    float y = (1.f - t) / (1.f + t);
    return x >= 0.f ? y : -y;
}

// ---- convert weights to bf16 + init cursors/bn8 (merged) -----------------
__global__ __launch_bounds__(256) void k_prep_w(
    const float* __restrict__ W_ih, const float* __restrict__ W_hh,
    const float* __restrict__ W_proj,
    ushort_t* __restrict__ Wih16, ushort_t* __restrict__ Whh16,
    ushort_t* __restrict__ WpT16,
    int* __restrict__ gcur, float* __restrict__ bn8, int NBK)
{
    int idx = blockIdx.x * 256 + threadIdx.x;
    if (idx < 49152) {
        Wih16[idx] = f2b(W_ih[idx]);
    } else if (idx < 98304) {
        int i = idx - 49152;
        Whh16[i] = f2b(W_hh[i]);
    } else if (idx < 114688) {
        int t = idx - 98304;           // WpT[j][k] = W_proj[k][j]
        int j = t >> 7, k = t & 127;
        WpT16[t] = f2b(W_proj[k * 128 + j]);
    } else if (idx < 114688 + 256) {
        int t = idx - 114688;
        if (t < NBK) gcur[t] = t * BCAP;
    } else if (idx < 114688 + 256 + 2048) {
        bn8[idx - 114688 - 256] = 0.f;
    }
}

// ---- FUSED: edge partition (blocks [0,nb_part)) + hv/scores (rest) -------
constexpr int EPT = 16;                        // edges per thread (part path)
__global__ __launch_bounds__(256, 2) void k_hv_part(
    const float* __restrict__ nf, const ushort_t* __restrict__ WpT16,
    const float* __restrict__ b_proj, const float* __restrict__ W_edge,
    ushort_t* __restrict__ nf16, ushort_t* __restrict__ hv16,
    float* __restrict__ s_d, float* __restrict__ s_s,
    const int* __restrict__ src, const int* __restrict__ dst,
    int* __restrict__ gcur, uint_t* __restrict__ pre_rec,
    int N, int NBK, int E, int nb_part)
{
    __shared__ ushort_t plds[16384];           // 32 KB (part aliases 2 KB)

    if ((int)blockIdx.x < nb_part) {
        // ================= partition path =================
        int* cnt   = (int*)plds;               // 256 ints
        int* gbase = cnt + 256;                // 256 ints
        int tid = threadIdx.x;
        int base = blockIdx.x * (256 * EPT);
        for (int i = tid; i < NBK; i += 256) cnt[i] = 0;
        __syncthreads();
        uint_t rec[EPT], pw[EPT];
#pragma unroll
        for (int i = 0; i < EPT; ++i) {
            int e = base + i * 256 + tid;
            uint_t r = 0, p = 0xFFFFFFFFu;
            if (e < E) {
                int s = src[e], t = dst[e];
                int b = t >> 8;
                int old = atomicAdd(&cnt[b], 1);
                r = (uint_t)s | ((uint_t)(t & 255) << 16);
                p = ((uint_t)b << 16) | (uint_t)old;
            }
            rec[i] = r; pw[i] = p;
        }
        __syncthreads();
        for (int bkt = tid; bkt < NBK; bkt += 256) {
            int c = cnt[bkt];
            gbase[bkt] = c ? atomicAdd(&gcur[bkt], c) : 0;
        }
        __syncthreads();
#pragma unroll
        for (int i = 0; i < EPT; ++i) {
            if (pw[i] != 0xFFFFFFFFu) {
                int b = pw[i] >> 16;
                int old = pw[i] & 0xFFFF;
                pre_rec[gbase[b] + old] = rec[i];
            }
        }
        return;
    }

    // ================= hv path =================
    int bid = blockIdx.x - nb_part;
    int w = threadIdx.x >> 6, lane = threadIdx.x & 63;
    int am = lane & 15, hi = lane >> 4, ak = hi * 8;

#pragma unroll
    for (int i = 0; i < 8; ++i) {
        int dl = (w * 8 + i) * 4 + hi;         // 0..127
        short8 v = *(const short8*)(WpT16 + (size_t)dl * 128 + am * 8);
        *(short8*)(plds + dl * 128 + ((am ^ (dl & 15)) * 8)) = v;
    }

    int r0 = bid * 64 + w * 16;
    int arow = r0 + am;
    bool aok = arow < N;
    short8 A[4];
    float pd = 0.f, ps = 0.f;
#pragma unroll
    for (int kf = 0; kf < 4; ++kf) {
        int ko = kf * 32 + ak;
        float4 f0 = {0,0,0,0}, f1 = {0,0,0,0};
        if (aok) {
            f0 = *(const float4*)(nf + (size_t)arow * 128 + ko);
            f1 = *(const float4*)(nf + (size_t)arow * 128 + ko + 4);
        }
        pd += f0.x * W_edge[ko]     + f0.y * W_edge[ko + 1]
            + f0.z * W_edge[ko + 2] + f0.w * W_edge[ko + 3]
            + f1.x * W_edge[ko + 4] + f1.y * W_edge[ko + 5]
            + f1.z * W_edge[ko + 6] + f1.w * W_edge[ko + 7];
        ps += f0.x * W_edge[128+ko]     + f0.y * W_edge[128+ko+1]
            + f0.z * W_edge[128+ko+2]   + f0.w * W_edge[128+ko+3]
            + f1.x * W_edge[128+ko+4]   + f1.y * W_edge[128+ko+5]
            + f1.z * W_edge[128+ko+6]   + f1.w * W_edge[128+ko+7];
        short8 a;
        a[0] = (short)f2b(f0.x); a[1] = (short)f2b(f0.y);
        a[2] = (short)f2b(f0.z); a[3] = (short)f2b(f0.w);
        a[4] = (short)f2b(f1.x); a[5] = (short)f2b(f1.y);
        a[6] = (short)f2b(f1.z); a[7] = (short)f2b(f1.w);
        A[kf] = a;
        if (aok) *(short8*)(nf16 + (size_t)arow * 128 + ko) = a;
    }
    pd += __shfl_xor(pd, 16); pd += __shfl_xor(pd, 32);
    ps += __shfl_xor(ps, 16); ps += __shfl_xor(ps, 32);
    if (hi == 0 && aok) { s_d[arow] = pd; s_s[arow] = ps; }

    __syncthreads();                           // LDS weights ready

    int crow0 = r0 + hi * 4;
#pragma unroll 2
    for (int nc = 0; nc < 8; ++nc) {
        f32x4 acc = {0.f, 0.f, 0.f, 0.f};
        int col = nc * 16 + am;
#pragma unroll
        for (int kf = 0; kf < 4; ++kf) {
            short8 B = *(const short8*)(plds + col * 128 + (((kf * 4 + hi) ^ am) * 8));
            acc = __builtin_amdgcn_mfma_f32_16x16x32_bf16(A[kf], B, acc, 0, 0, 0);
        }
        float b = b_proj[col];
#pragma unroll
        for (int r = 0; r < 4; ++r) {
            int grow = crow0 + r;
            if (grow < N) hv16[(size_t)grow * 128 + col] = f2b(acc[r] + b);
        }
    }
}

// ---- phase 2: per-bucket node sort + ev/den + CSR write ------------------
__global__ __launch_bounds__(256) void k_bucket(
    const uint_t* __restrict__ pre_rec, const int* __restrict__ gcur,
    const float* __restrict__ s_d, const float* __restrict__ s_s,
    const float* __restrict__ b_edge,
    int* __restrict__ row_start, int* __restrict__ row_cnt,
    uint2* __restrict__ edge_rec, float* __restrict__ den, int N)
{
    __shared__ int cnt[256], offx[256], cur[256], sdata[256];
    __shared__ float sdl[256], denl[256];
    int b = blockIdx.x, tid = threadIdx.x;
    int node = (b << 8) + tid;
    cnt[tid] = 0; cur[tid] = 0; denl[tid] = 0.f;
    sdl[tid] = (node < N) ? s_d[node] : 0.f;
    __syncthreads();
    int rs0 = b * BCAP, rs1 = gcur[b];
    for (int i = rs0 + tid; i < rs1; i += 256)
        atomicAdd(&cnt[(pre_rec[i] >> 16) & 255], 1);
    __syncthreads();
    int v = cnt[tid];
    int incl = v;
    sdata[tid] = incl; __syncthreads();
#pragma unroll
    for (int off = 1; off < 256; off <<= 1) {
        int add = (tid >= off) ? sdata[tid - off] : 0;
        __syncthreads();
        incl += add;
        sdata[tid] = incl;
        __syncthreads();
    }
    offx[tid] = incl - v;
    if (node < N) {
        row_start[node] = rs0 + incl - v;
        row_cnt[node] = v;
    }
    __syncthreads();
    float bias = b_edge[0];
    for (int i = rs0 + tid; i < rs1; i += 256) {
        uint_t rec = pre_rec[i];
        int sidx = rec & 0xFFFF;
        int dl = (rec >> 16) & 255;
        float l = sdl[dl] + s_s[sidx] + bias;
        l = l > 0.f ? l : 0.01f * l;
        float ev = __expf(l);
        int lp = atomicAdd(&cur[dl], 1);
        uint2 r;
        r.x = (uint_t)sidx;
        r.y = __float_as_uint(ev);
        edge_rec[rs0 + offx[dl] + lp] = r;
        atomicAdd(&denl[dl], ev);
    }
    __syncthreads();
    if (node < N) den[node] = denl[tid];
}

// ---- aggregate: half-wave per node (2 nodes/wave), uint2 row gathers -----
__global__ __launch_bounds__(256) void k_agg4(
    const ushort_t* __restrict__ hv16, const int* __restrict__ row_start,
    const int* __restrict__ row_cnt, const float* __restrict__ den,
    const uint2* __restrict__ edge_rec, ushort_t* __restrict__ ctx16, int N)
{
    __shared__ uint2 elds[8][128];             // 8 nodes x <=128 edges = 8 KB
    int w = threadIdx.x >> 6, lane = threadIdx.x & 63;
    int half = lane >> 5;                      // 0 or 1
    int hl = lane & 31;                        // lane within half-wave
    int nid = w * 2 + half;                    // node slot 0..7
    int v = blockIdx.x * 8 + nid;
    bool vok = v < N;

    int beg = 0, cnt = 0;
    float dv = 0.f;
    if (vok) {
        beg = row_start[v];
        cnt = row_cnt[v];
        dv = den[v];
        int cap0 = min(cnt, 128);
        for (int c = hl; c < cap0; c += 32)
            elds[nid][c] = edge_rec[beg + c];
    }
    float inv = dv > 0.f ? 1.f / dv : 0.f;

    float c0 = 0.f, c1 = 0.f, c2 = 0.f, c3 = 0.f;
    int cap = min(cnt, 128);
    for (int t0 = 0; t0 < cap; t0 += 8) {
        uint2 p[8];
        float wt[8];
#pragma unroll
        for (int k = 0; k < 8; ++k) {
            int tt = t0 + k;
            uint2 er = elds[nid][tt < cap ? tt : 0];
            wt[k] = (tt < cap) ? fmaf(__uint_as_float(er.y), inv, 1.0f) : 0.f;
            p[k] = ((const uint2*)(hv16 + ((size_t)er.x << 7)))[hl];
        }
#pragma unroll
        for (int k = 0; k < 8; ++k) {
            c0 = fmaf(b2f((ushort_t)p[k].x), wt[k], c0);
            c1 = fmaf(b2f((ushort_t)(p[k].x >> 16)), wt[k], c1);
            c2 = fmaf(b2f((ushort_t)p[k].y), wt[k], c2);
            c3 = fmaf(b2f((ushort_t)(p[k].y >> 16)), wt[k], c3);
        }
    }
    for (int c = 128; c < cnt; ++c) {          // ~never taken (deg>128)
        uint2 er = edge_rec[beg + c];
        float wt2 = fmaf(__uint_as_float(er.y), inv, 1.0f);
        uint2 p2 = ((const uint2*)(hv16 + ((size_t)er.x << 7)))[hl];
        c0 = fmaf(b2f((ushort_t)p2.x), wt2, c0);
        c1 = fmaf(b2f((ushort_t)(p2.x >> 16)), wt2, c1);
        c2 = fmaf(b2f((ushort_t)p2.y), wt2, c2);
        c3 = fmaf(b2f((ushort_t)(p2.y >> 16)), wt2, c3);
    }
    if (!vok) return;
    c0 = c0 > 0.f ? c0 : expm1f(c0);
    c1 = c1 > 0.f ? c1 : expm1f(c1);
    c2 = c2 > 0.f ? c2 : expm1f(c2);
    c3 = c3 > 0.f ? c3 : expm1f(c3);
    uint2 outp;
    outp.x = (uint_t)f2b(c0) | ((uint_t)f2b(c1) << 16);
    outp.y = (uint_t)f2b(c2) | ((uint_t)f2b(c3) << 16);
    ((uint2*)ctx16)[(size_t)v * 32 + hl] = outp;
}

// ---- GRU + relu + BN stats + grid.sync + BN normalize (cooperative) ------
// grid = (128 rowblocks, 2 colgroups) = 256 blocks, exactly 1/CU.
__global__ __launch_bounds__(1024, 1) void k_gru_bn(
    const ushort_t* __restrict__ ctx16, const ushort_t* __restrict__ nf16,
    const ushort_t* __restrict__ Wih16, const ushort_t* __restrict__ Whh16,
    const float* __restrict__ b_ih, const float* __restrict__ b_hh,
    float* __restrict__ out, float* __restrict__ bn8,
    const float* __restrict__ gamma, const float* __restrict__ beta, int N)
{
    __shared__ ushort_t wlds[6 * 8192];    // 96 KB
    __shared__ float bnsum[2][16][64];     // 8 KB
    __shared__ float a_s[64], c_s[64];     // 512 B
    int tid = threadIdx.x;
    int w = tid >> 6, lane = tid & 63;
    int am = lane & 15, hi = lane >> 4, ak = hi * 8;
    int g64 = blockIdx.y * 64;

    for (int q = tid; q < 6144; q += 1024) {
        int m = q >> 10;
        int rem = q & 1023;
        int col = rem >> 4;
        int kc = rem & 15;
        const ushort_t* sb = (m & 1) ? Whh16 : Wih16;
        short8 v = *(const short8*)(sb + (size_t)((m >> 1) * 128 + g64 + col) * 128 + kc * 8);
        *(short8*)(wlds + m * 8192 + col * 128 + ((kc ^ (col & 15)) * 8)) = v;
    }
    __syncthreads();

    float br_[4], bz_[4], bi_[4], bh_[4];
#pragma unroll
    for (int cf = 0; cf < 4; ++cf) {
        int dgl = g64 + cf * 16 + am;
        br_[cf] = b_ih[dgl] + b_hh[dgl];
        bz_[cf] = b_ih[128 + dgl] + b_hh[128 + dgl];
        bi_[cf] = b_ih[256 + dgl];
        bh_[cf] = b_hh[256 + dgl];
    }
    float cs[4] = {0,0,0,0}, cs2[4] = {0,0,0,0};
    float hreg[2][4][4];                   // static-indexed (2 row groups max)

#pragma unroll
    for (int g = 0; g < 2; ++g) {
        int r0 = blockIdx.x * 256 + g * 32768;   // gridDim.x==128 fixed
        if (r0 >= N) continue;
        int rbase = r0 + w * 16;
        int arow = rbase + am;
        bool aok = arow < N;
        short8 z8 = {0,0,0,0,0,0,0,0};
        short8 Ac[4], An[4];
#pragma unroll
        for (int kf = 0; kf < 4; ++kf) {
            size_t off = (size_t)arow * 128 + kf * 32 + ak;
            Ac[kf] = aok ? *(const short8*)(ctx16 + off) : z8;
            An[kf] = aok ? *(const short8*)(nf16 + off) : z8;
        }
        int crow0 = rbase + hi * 4;
#pragma unroll 1
        for (int cf = 0; cf < 4; ++cf) {
            int dgl = g64 + cf * 16 + am;
            float hp_pre[4];
#pragma unroll
            for (int r = 0; r < 4; ++r) {
                int grow = crow0 + r;
                hp_pre[r] = (grow < N) ? b2f(nf16[(size_t)grow * 128 + dgl]) : 0.f;
            }
            f32x4 racc = {0,0,0,0}, zacc = {0,0,0,0};
            f32x4 iacc = {0,0,0,0}, hacc = {0,0,0,0};
#pragma unroll
            for (int kf = 0; kf < 4; ++kf) {
                const ushort_t* bp = wlds + (cf * 16 + am) * 128
                                   + ((((kf << 2) + hi) ^ am) * 8);
                short8 Br = *(const short8*)(bp + 0 * 8192);
                short8 Cr = *(const short8*)(bp + 1 * 8192);
                short8 Bz = *(const short8*)(bp + 2 * 8192);
                short8 Cz = *(const short8*)(bp + 3 * 8192);
                short8 Bi = *(const short8*)(bp + 4 * 8192);
                short8 Ch = *(const short8*)(bp + 5 * 8192);
                racc = __builtin_amdgcn_mfma_f32_16x16x32_bf16(Ac[kf], Br, racc, 0, 0, 0);
                racc = __builtin_amdgcn_mfma_f32_16x16x32_bf16(An[kf], Cr, racc, 0, 0, 0);
                zacc = __builtin_amdgcn_mfma_f32_16x16x32_bf16(Ac[kf], Bz, zacc, 0, 0, 0);
                zacc = __builtin_amdgcn_mfma_f32_16x16x32_bf16(An[kf], Cz, zacc, 0, 0, 0);
                iacc = __builtin_amdgcn_mfma_f32_16x16x32_bf16(Ac[kf], Bi, iacc, 0, 0, 0);
                hacc = __builtin_amdgcn_mfma_f32_16x16x32_bf16(An[kf], Ch, hacc, 0, 0, 0);
            }
#pragma unroll
            for (int r = 0; r < 4; ++r) {
                int grow = crow0 + r;
                float rv = sigm(racc[r] + br_[cf]);
                float zv = sigm(zacc[r] + bz_[cf]);
                float nv = tanh_(iacc[r] + bi_[cf] + rv * (hacc[r] + bh_[cf]));
                float h = (1.f - zv) * nv + zv * hp_pre[r];
                h = fmaxf(h, 0.f);
                if (grow >= N) h = 0.f;
                hreg[g][cf][r] = h;
                cs[cf] += h;
                cs2[cf] = fmaf(h, h, cs2[cf]);
            }
        }
    }

    // BN reduce: 4 hi-groups via shfl, 16 waves via LDS, 1 atomic per col
#pragma unroll
    for (int cf = 0; cf < 4; ++cf) {
        cs[cf]  += __shfl_xor(cs[cf], 16);  cs[cf]  += __shfl_xor(cs[cf], 32);
        cs2[cf] += __shfl_xor(cs2[cf], 16); cs2[cf] += __shfl_xor(cs2[cf], 32);
        if (hi == 0) {
            bnsum[0][w][cf * 16 + am] = cs[cf];
            bnsum[1][w][cf * 16 + am] = cs2[cf];
        }
    }
    __syncthreads();
    int bin = (blockIdx.x & 7) * 256;
    if (tid < 64) {
        float s = 0.f;
#pragma unroll
        for (int wv = 0; wv < 16; ++wv) s += bnsum[0][wv][tid];
        atomicAdd(&bn8[bin + g64 + tid], s);
    } else if (tid < 128) {
        int c2 = tid - 64;
        float s2 = 0.f;
#pragma unroll
        for (int wv = 0; wv < 16; ++wv) s2 += bnsum[1][wv][c2];
        atomicAdd(&bn8[bin + 128 + g64 + c2], s2);
    }

    cg::this_grid().sync();                // all bn8 contributions visible

    if (tid < 64) {
        int gc = g64 + tid;
        float s = 0.f, s2 = 0.f;
#pragma unroll
        for (int b = 0; b < 8; ++b) {
            s  += bn8[b * 256 + gc];
            s2 += bn8[b * 256 + 128 + gc];
        }
        float invN = 1.f / (float)N;
        float mean = s * invN;
        float var = s2 * invN - mean * mean;
        float a = rsqrtf(var + 1e-5f) * gamma[gc];
        a_s[tid] = a;
        c_s[tid] = beta[gc] - mean * a;
    }
    __syncthreads();

    // write normalized output (single 25.6 MB write total)
#pragma unroll
    for (int g = 0; g < 2; ++g) {
        int r0 = blockIdx.x * 256 + g * 32768;
        if (r0 >= N) continue;
        int crow0 = r0 + w * 16 + hi * 4;
#pragma unroll
        for (int cf = 0; cf < 4; ++cf) {
            int lc = cf * 16 + am;
            int dgl = g64 + lc;
            float a = a_s[lc], c = c_s[lc];
#pragma unroll
            for (int r = 0; r < 4; ++r) {
                int grow = crow0 + r;
                if (grow < N)
                    out[(size_t)grow * 128 + dgl] = hreg[g][cf][r] * a + c;
            }
        }
    }
}

// ---- host launcher -------------------------------------------------------
extern "C" void kernel_launch(void* const* d_in, const int* in_sizes, int n_in,
                              void* d_out, int out_size, void* d_ws, size_t ws_size,
                              hipStream_t stream)
{
    const float* nf     = (const float*)d_in[0];
    const int*   src    = (const int*)  d_in[1];
    const int*   dst    = (const int*)  d_in[2];
    const float* W_edge = (const float*)d_in[3];
    const float* b_edge = (const float*)d_in[4];
    const float* W_proj = (const float*)d_in[5];
    const float* b_proj = (const float*)d_in[6];
    const float* W_ih   = (const float*)d_in[7];
    const float* W_hh   = (const float*)d_in[8];
    const float* b_ih   = (const float*)d_in[9];
    const float* b_hh   = (const float*)d_in[10];
    const float* bn_g   = (const float*)d_in[11];
    const float* bn_b   = (const float*)d_in[12];

    const int N   = in_sizes[0] / D;   // 50000 (must be <= 65536 for 16-bit src)
    const int E   = in_sizes[1];       // 600000
    const int NBK = (N + 255) >> 8;    // 196 buckets

    float* ws = (float*)d_ws;
    float* s_d        = ws;                                 // N
    float* s_s        = ws + (size_t)N;                     // N
    float* den        = ws + (size_t)2 * N;                 // N
    int*   row_start  = (int*)(ws + (size_t)3 * N);         // N
    int*   row_cnt    = (int*)(ws + (size_t)4 * N);         // N
    int*   gcur       = (int*)(ws + (size_t)5 * N);         // 256
    float* bn8        = ws + (size_t)5 * N + 256;           // 2048
    uint_t* pre_rec   = (uint_t*)(ws + (size_t)5 * N + 2304);            // NBK*BCAP
    uint2*  edge_rec  = (uint2*)(pre_rec + (size_t)NBK * BCAP);          // NBK*BCAP*8B
    ushort_t* nf16    = (ushort_t*)(edge_rec + (size_t)NBK * BCAP);
    ushort_t* hv16    = nf16 + (size_t)N * 128;
    ushort_t* ctx16   = hv16 + (size_t)N * 128;
    ushort_t* Wih16   = ctx16 + (size_t)N * 128;
    ushort_t* Whh16   = Wih16 + 384 * 128;
    ushort_t* WpT16   = Whh16 + 384 * 128;

    float* outp = (float*)d_out;

    int nb_part = (E + 256 * EPT - 1) / (256 * EPT);   // 147
    int nb_hv   = (N + 63) / 64;                       // 782

    k_prep_w<<<(114688 + 2304 + 255) / 256, 256, 0, stream>>>(
        W_ih, W_hh, W_proj, Wih16, Whh16, WpT16, gcur, bn8, NBK);
    k_hv_part<<<nb_part + nb_hv, 256, 0, stream>>>(
        nf, WpT16, b_proj, W_edge, nf16, hv16, s_d, s_s,
        src, dst, gcur, pre_rec, N, NBK, E, nb_part);
    k_bucket<<<NBK, 256, 0, stream>>>(pre_rec, gcur, s_d, s_s, b_edge,
                                      row_start, row_cnt, edge_rec, den, N);
    k_agg4<<<(N + 7) / 8, 256, 0, stream>>>(hv16, row_start, row_cnt, den,
                                            edge_rec, ctx16, N);
    {
        int Nv = N;
        void* args[] = {
            (void*)&ctx16, (void*)&nf16, (void*)&Wih16, (void*)&Whh16,
            (void*)&b_ih, (void*)&b_hh, (void*)&outp, (void*)&bn8,
            (void*)&bn_g, (void*)&bn_b, (void*)&Nv
        };
        hipLaunchCooperativeKernel((const void*)k_gru_bn, dim3(128, 2),
                                   dim3(1024), args, 0, stream);
    }
}

// Round 24
// 119.990 us; speedup vs baseline: 1.2755x; 1.2755x over previous
//
#include <hip/hip_runtime.h>
#include <math.h>

constexpr int D = 128;
constexpr int BCAP = 4096;                 // per-bucket capacity (max ~3400)

typedef __attribute__((ext_vector_type(8))) short short8;
typedef __attribute__((ext_vector_type(4))) float f32x4;
typedef unsigned short ushort_t;
typedef unsigned int uint_t;

__device__ inline ushort_t f2b(float x) {          // fp32 -> bf16 RNE
    uint_t u = __float_as_uint(x);
    uint_t r = u + 0x7fffu + ((u >> 16) & 1u);
    return (ushort_t)(r >> 16);
}
__device__ inline float b2f(ushort_t b) { return __uint_as_float(((uint_t)b) << 16); }

__device__ inline float sigm(float x) { return 1.f / (1.f + __expf(-x)); }
__device__ inline float tanh_(float x) {
    float t = __expf(-2.f * fabsf(x));
    float y = (1.f - t) / (1.f + t);
    return x >= 0.f ? y : -y;
}

// ---- convert weights to bf16 + init cursors/bn8 (merged) -----------------
__global__ __launch_bounds__(256) void k_prep_w(
    const float* __restrict__ W_ih, const float* __restrict__ W_hh,
    const float* __restrict__ W_proj,
    ushort_t* __restrict__ Wih16, ushort_t* __restrict__ Whh16,
    ushort_t* __restrict__ WpT16,
    int* __restrict__ gcur, float* __restrict__ bn8, int NBK)
{
    int idx = blockIdx.x * 256 + threadIdx.x;
    if (idx < 49152) {
        Wih16[idx] = f2b(W_ih[idx]);
    } else if (idx < 98304) {
        int i = idx - 49152;
        Whh16[i] = f2b(W_hh[i]);
    } else if (idx < 114688) {
        int t = idx - 98304;           // WpT[j][k] = W_proj[k][j]
        int j = t >> 7, k = t & 127;
        WpT16[t] = f2b(W_proj[k * 128 + j]);
    } else if (idx < 114688 + 256) {
        int t = idx - 114688;
        if (t < NBK) gcur[t] = t * BCAP;
    } else if (idx < 114688 + 256 + 2048) {
        bn8[idx - 114688 - 256] = 0.f;
    }
}

// ---- FUSED: edge partition (blocks [0,nb_part)) + hv/scores (rest) -------
constexpr int EPT = 16;                        // edges per thread (part path)
__global__ __launch_bounds__(256, 2) void k_hv_part(
    const float* __restrict__ nf, const ushort_t* __restrict__ WpT16,
    const float* __restrict__ b_proj, const float* __restrict__ W_edge,
    ushort_t* __restrict__ nf16, ushort_t* __restrict__ hv16,
    float* __restrict__ s_d, float* __restrict__ s_s,
    const int* __restrict__ src, const int* __restrict__ dst,
    int* __restrict__ gcur, uint_t* __restrict__ pre_rec,
    int N, int NBK, int E, int nb_part)
{
    __shared__ ushort_t plds[16384];           // 32 KB (part aliases 2 KB)

    if ((int)blockIdx.x < nb_part) {
        // ================= partition path =================
        int* cnt   = (int*)plds;               // 256 ints
        int* gbase = cnt + 256;                // 256 ints
        int tid = threadIdx.x;
        int base = blockIdx.x * (256 * EPT);
        for (int i = tid; i < NBK; i += 256) cnt[i] = 0;
        __syncthreads();
        uint_t rec[EPT], pw[EPT];
#pragma unroll
        for (int i = 0; i < EPT; ++i) {
            int e = base + i * 256 + tid;
            uint_t r = 0, p = 0xFFFFFFFFu;
            if (e < E) {
                int s = src[e], t = dst[e];
                int b = t >> 8;
                int old = atomicAdd(&cnt[b], 1);
                r = (uint_t)s | ((uint_t)(t & 255) << 16);
                p = ((uint_t)b << 16) | (uint_t)old;
            }
            rec[i] = r; pw[i] = p;
        }
        __syncthreads();
        for (int bkt = tid; bkt < NBK; bkt += 256) {
            int c = cnt[bkt];
            gbase[bkt] = c ? atomicAdd(&gcur[bkt], c) : 0;
        }
        __syncthreads();
#pragma unroll
        for (int i = 0; i < EPT; ++i) {
            if (pw[i] != 0xFFFFFFFFu) {
                int b = pw[i] >> 16;
                int old = pw[i] & 0xFFFF;
                pre_rec[gbase[b] + old] = rec[i];
            }
        }
        return;
    }

    // ================= hv path =================
    int bid = blockIdx.x - nb_part;
    int w = threadIdx.x >> 6, lane = threadIdx.x & 63;
    int am = lane & 15, hi = lane >> 4, ak = hi * 8;

#pragma unroll
    for (int i = 0; i < 8; ++i) {
        int dl = (w * 8 + i) * 4 + hi;         // 0..127
        short8 v = *(const short8*)(WpT16 + (size_t)dl * 128 + am * 8);
        *(short8*)(plds + dl * 128 + ((am ^ (dl & 15)) * 8)) = v;
    }

    int r0 = bid * 64 + w * 16;
    int arow = r0 + am;
    bool aok = arow < N;
    short8 A[4];
    float pd = 0.f, ps = 0.f;
#pragma unroll
    for (int kf = 0; kf < 4; ++kf) {
        int ko = kf * 32 + ak;
        float4 f0 = {0,0,0,0}, f1 = {0,0,0,0};
        if (aok) {
            f0 = *(const float4*)(nf + (size_t)arow * 128 + ko);
            f1 = *(const float4*)(nf + (size_t)arow * 128 + ko + 4);
        }
        pd += f0.x * W_edge[ko]     + f0.y * W_edge[ko + 1]
            + f0.z * W_edge[ko + 2] + f0.w * W_edge[ko + 3]
            + f1.x * W_edge[ko + 4] + f1.y * W_edge[ko + 5]
            + f1.z * W_edge[ko + 6] + f1.w * W_edge[ko + 7];
        ps += f0.x * W_edge[128+ko]     + f0.y * W_edge[128+ko+1]
            + f0.z * W_edge[128+ko+2]   + f0.w * W_edge[128+ko+3]
            + f1.x * W_edge[128+ko+4]   + f1.y * W_edge[128+ko+5]
            + f1.z * W_edge[128+ko+6]   + f1.w * W_edge[128+ko+7];
        short8 a;
        a[0] = (short)f2b(f0.x); a[1] = (short)f2b(f0.y);
        a[2] = (short)f2b(f0.z); a[3] = (short)f2b(f0.w);
        a[4] = (short)f2b(f1.x); a[5] = (short)f2b(f1.y);
        a[6] = (short)f2b(f1.z); a[7] = (short)f2b(f1.w);
        A[kf] = a;
        if (aok) *(short8*)(nf16 + (size_t)arow * 128 + ko) = a;
    }
    pd += __shfl_xor(pd, 16); pd += __shfl_xor(pd, 32);
    ps += __shfl_xor(ps, 16); ps += __shfl_xor(ps, 32);
    if (hi == 0 && aok) { s_d[arow] = pd; s_s[arow] = ps; }

    __syncthreads();                           // LDS weights ready

    int crow0 = r0 + hi * 4;
#pragma unroll 2
    for (int nc = 0; nc < 8; ++nc) {
        f32x4 acc = {0.f, 0.f, 0.f, 0.f};
        int col = nc * 16 + am;
#pragma unroll
        for (int kf = 0; kf < 4; ++kf) {
            short8 B = *(const short8*)(plds + col * 128 + (((kf * 4 + hi) ^ am) * 8));
            acc = __builtin_amdgcn_mfma_f32_16x16x32_bf16(A[kf], B, acc, 0, 0, 0);
        }
        float b = b_proj[col];
#pragma unroll
        for (int r = 0; r < 4; ++r) {
            int grow = crow0 + r;
            if (grow < N) hv16[(size_t)grow * 128 + col] = f2b(acc[r] + b);
        }
    }
}

// ---- phase 2: per-bucket node sort + ev/den + CSR write ------------------
__global__ __launch_bounds__(256) void k_bucket(
    const uint_t* __restrict__ pre_rec, const int* __restrict__ gcur,
    const float* __restrict__ s_d, const float* __restrict__ s_s,
    const float* __restrict__ b_edge,
    int* __restrict__ row_start, int* __restrict__ row_cnt,
    uint2* __restrict__ edge_rec, float* __restrict__ den, int N)
{
    __shared__ int cnt[256], offx[256], cur[256], sdata[256];
    __shared__ float sdl[256], denl[256];
    int b = blockIdx.x, tid = threadIdx.x;
    int node = (b << 8) + tid;
    cnt[tid] = 0; cur[tid] = 0; denl[tid] = 0.f;
    sdl[tid] = (node < N) ? s_d[node] : 0.f;
    __syncthreads();
    int rs0 = b * BCAP, rs1 = gcur[b];
    for (int i = rs0 + tid; i < rs1; i += 256)
        atomicAdd(&cnt[(pre_rec[i] >> 16) & 255], 1);
    __syncthreads();
    int v = cnt[tid];
    int incl = v;
    sdata[tid] = incl; __syncthreads();
#pragma unroll
    for (int off = 1; off < 256; off <<= 1) {
        int add = (tid >= off) ? sdata[tid - off] : 0;
        __syncthreads();
        incl += add;
        sdata[tid] = incl;
        __syncthreads();
    }
    offx[tid] = incl - v;
    if (node < N) {
        row_start[node] = rs0 + incl - v;
        row_cnt[node] = v;
    }
    __syncthreads();
    float bias = b_edge[0];
    for (int i = rs0 + tid; i < rs1; i += 256) {
        uint_t rec = pre_rec[i];
        int sidx = rec & 0xFFFF;
        int dl = (rec >> 16) & 255;
        float l = sdl[dl] + s_s[sidx] + bias;
        l = l > 0.f ? l : 0.01f * l;
        float ev = __expf(l);
        int lp = atomicAdd(&cur[dl], 1);
        uint2 r;
        r.x = (uint_t)sidx;
        r.y = __float_as_uint(ev);
        edge_rec[rs0 + offx[dl] + lp] = r;
        atomicAdd(&denl[dl], ev);
    }
    __syncthreads();
    if (node < N) den[node] = denl[tid];
}

// ---- aggregate: half-wave per node (2 nodes/wave), uint2 row gathers -----
__global__ __launch_bounds__(256) void k_agg4(
    const ushort_t* __restrict__ hv16, const int* __restrict__ row_start,
    const int* __restrict__ row_cnt, const float* __restrict__ den,
    const uint2* __restrict__ edge_rec, ushort_t* __restrict__ ctx16, int N)
{
    __shared__ uint2 elds[8][128];             // 8 nodes x <=128 edges = 8 KB
    int w = threadIdx.x >> 6, lane = threadIdx.x & 63;
    int half = lane >> 5;                      // 0 or 1
    int hl = lane & 31;                        // lane within half-wave
    int nid = w * 2 + half;                    // node slot 0..7
    int v = blockIdx.x * 8 + nid;
    bool vok = v < N;

    int beg = 0, cnt = 0;
    float dv = 0.f;
    if (vok) {
        beg = row_start[v];
        cnt = row_cnt[v];
        dv = den[v];
        int cap0 = min(cnt, 128);
        for (int c = hl; c < cap0; c += 32)
            elds[nid][c] = edge_rec[beg + c];
    }
    float inv = dv > 0.f ? 1.f / dv : 0.f;

    float c0 = 0.f, c1 = 0.f, c2 = 0.f, c3 = 0.f;
    int cap = min(cnt, 128);
    for (int t0 = 0; t0 < cap; t0 += 8) {
        uint2 p[8];
        float wt[8];
#pragma unroll
        for (int k = 0; k < 8; ++k) {
            int tt = t0 + k;
            uint2 er = elds[nid][tt < cap ? tt : 0];
            wt[k] = (tt < cap) ? fmaf(__uint_as_float(er.y), inv, 1.0f) : 0.f;
            p[k] = ((const uint2*)(hv16 + ((size_t)er.x << 7)))[hl];
        }
#pragma unroll
        for (int k = 0; k < 8; ++k) {
            c0 = fmaf(b2f((ushort_t)p[k].x), wt[k], c0);
            c1 = fmaf(b2f((ushort_t)(p[k].x >> 16)), wt[k], c1);
            c2 = fmaf(b2f((ushort_t)p[k].y), wt[k], c2);
            c3 = fmaf(b2f((ushort_t)(p[k].y >> 16)), wt[k], c3);
        }
    }
    for (int c = 128; c < cnt; ++c) {          // ~never taken (deg>128)
        uint2 er = edge_rec[beg + c];
        float wt2 = fmaf(__uint_as_float(er.y), inv, 1.0f);
        uint2 p2 = ((const uint2*)(hv16 + ((size_t)er.x << 7)))[hl];
        c0 = fmaf(b2f((ushort_t)p2.x), wt2, c0);
        c1 = fmaf(b2f((ushort_t)(p2.x >> 16)), wt2, c1);
        c2 = fmaf(b2f((ushort_t)p2.y), wt2, c2);
        c3 = fmaf(b2f((ushort_t)(p2.y >> 16)), wt2, c3);
    }
    if (!vok) return;
    c0 = c0 > 0.f ? c0 : expm1f(c0);
    c1 = c1 > 0.f ? c1 : expm1f(c1);
    c2 = c2 > 0.f ? c2 : expm1f(c2);
    c3 = c3 > 0.f ? c3 : expm1f(c3);
    uint2 outp;
    outp.x = (uint_t)f2b(c0) | ((uint_t)f2b(c1) << 16);
    outp.y = (uint_t)f2b(c2) | ((uint_t)f2b(c3) << 16);
    ((uint2*)ctx16)[(size_t)v * 32 + hl] = outp;
}

// ---- GRU + relu + BN-stats: stage-once 96KB, 16 waves, grid-stride -------
__global__ __launch_bounds__(1024, 1) void k_gru_mfma(
    const ushort_t* __restrict__ ctx16, const ushort_t* __restrict__ nf16,
    const ushort_t* __restrict__ Wih16, const ushort_t* __restrict__ Whh16,
    const float* __restrict__ b_ih, const float* __restrict__ b_hh,
    float* __restrict__ out, float* __restrict__ bn8, int N)
{
    __shared__ ushort_t wlds[6 * 8192];    // 96 KB: [mat][col 64][k 128] swz
    __shared__ float bnsum[2][16][64];     // 8 KB
    int tid = threadIdx.x;
    int w = tid >> 6, lane = tid & 63;
    int am = lane & 15, hi = lane >> 4, ak = hi * 8;
    int g64 = blockIdx.y * 64;

    for (int q = tid; q < 6144; q += 1024) {
        int m = q >> 10;
        int rem = q & 1023;
        int col = rem >> 4;
        int kc = rem & 15;
        const ushort_t* sb = (m & 1) ? Whh16 : Wih16;
        short8 v = *(const short8*)(sb + (size_t)((m >> 1) * 128 + g64 + col) * 128 + kc * 8);
        *(short8*)(wlds + m * 8192 + col * 128 + ((kc ^ (col & 15)) * 8)) = v;
    }
    __syncthreads();

    float br_[4], bz_[4], bi_[4], bh_[4];
#pragma unroll
    for (int cf = 0; cf < 4; ++cf) {
        int dgl = g64 + cf * 16 + am;
        br_[cf] = b_ih[dgl] + b_hh[dgl];
        bz_[cf] = b_ih[128 + dgl] + b_hh[128 + dgl];
        bi_[cf] = b_ih[256 + dgl];
        bh_[cf] = b_hh[256 + dgl];
    }
    float cs[4] = {0,0,0,0}, cs2[4] = {0,0,0,0};

    for (int r0 = blockIdx.x * 256; r0 < N; r0 += gridDim.x * 256) {
        int rbase = r0 + w * 16;
        int arow = rbase + am;
        bool aok = arow < N;
        short8 z8 = {0,0,0,0,0,0,0,0};
        short8 Ac[4], An[4];
#pragma unroll
        for (int kf = 0; kf < 4; ++kf) {
            size_t off = (size_t)arow * 128 + kf * 32 + ak;
            Ac[kf] = aok ? *(const short8*)(ctx16 + off) : z8;
            An[kf] = aok ? *(const short8*)(nf16 + off) : z8;
        }
        int crow0 = rbase + hi * 4;
#pragma unroll 1
        for (int cf = 0; cf < 4; ++cf) {
            int dgl = g64 + cf * 16 + am;
            float hp_pre[4];
#pragma unroll
            for (int r = 0; r < 4; ++r) {
                int grow = crow0 + r;
                hp_pre[r] = (grow < N) ? b2f(nf16[(size_t)grow * 128 + dgl]) : 0.f;
            }
            f32x4 racc = {0,0,0,0}, zacc = {0,0,0,0};
            f32x4 iacc = {0,0,0,0}, hacc = {0,0,0,0};
#pragma unroll
            for (int kf = 0; kf < 4; ++kf) {
                const ushort_t* bp = wlds + (cf * 16 + am) * 128
                                   + ((((kf << 2) + hi) ^ am) * 8);
                short8 Br = *(const short8*)(bp + 0 * 8192);
                short8 Cr = *(const short8*)(bp + 1 * 8192);
                short8 Bz = *(const short8*)(bp + 2 * 8192);
                short8 Cz = *(const short8*)(bp + 3 * 8192);
                short8 Bi = *(const short8*)(bp + 4 * 8192);
                short8 Ch = *(const short8*)(bp + 5 * 8192);
                racc = __builtin_amdgcn_mfma_f32_16x16x32_bf16(Ac[kf], Br, racc, 0, 0, 0);
                racc = __builtin_amdgcn_mfma_f32_16x16x32_bf16(An[kf], Cr, racc, 0, 0, 0);
                zacc = __builtin_amdgcn_mfma_f32_16x16x32_bf16(Ac[kf], Bz, zacc, 0, 0, 0);
                zacc = __builtin_amdgcn_mfma_f32_16x16x32_bf16(An[kf], Cz, zacc, 0, 0, 0);
                iacc = __builtin_amdgcn_mfma_f32_16x16x32_bf16(Ac[kf], Bi, iacc, 0, 0, 0);
                hacc = __builtin_amdgcn_mfma_f32_16x16x32_bf16(An[kf], Ch, hacc, 0, 0, 0);
            }
#pragma unroll
            for (int r = 0; r < 4; ++r) {
                int grow = crow0 + r;
                float rv = sigm(racc[r] + br_[cf]);
                float zv = sigm(zacc[r] + bz_[cf]);
                float nv = tanh_(iacc[r] + bi_[cf] + rv * (hacc[r] + bh_[cf]));
                float h = (1.f - zv) * nv + zv * hp_pre[r];
                h = fmaxf(h, 0.f);
                if (grow < N) out[(size_t)grow * 128 + dgl] = h;
                else h = 0.f;
                cs[cf] += h;
                cs2[cf] = fmaf(h, h, cs2[cf]);
            }
        }
    }

#pragma unroll
    for (int cf = 0; cf < 4; ++cf) {
        cs[cf]  += __shfl_xor(cs[cf], 16);  cs[cf]  += __shfl_xor(cs[cf], 32);
        cs2[cf] += __shfl_xor(cs2[cf], 16); cs2[cf] += __shfl_xor(cs2[cf], 32);
        if (hi == 0) {
            bnsum[0][w][cf * 16 + am] = cs[cf];
            bnsum[1][w][cf * 16 + am] = cs2[cf];
        }
    }
    __syncthreads();
    int bin = (blockIdx.x & 7) * 256;
    if (tid < 64) {
        float s = 0.f;
#pragma unroll
        for (int wv = 0; wv < 16; ++wv) s += bnsum[0][wv][tid];
        atomicAdd(&bn8[bin + g64 + tid], s);
    } else if (tid < 128) {
        int c2 = tid - 64;
        float s2 = 0.f;
#pragma unroll
        for (int wv = 0; wv < 16; ++wv) s2 += bnsum[1][wv][c2];
        atomicAdd(&bn8[bin + 128 + g64 + c2], s2);
    }
}

// ---- BatchNorm normalize: LDS-cached coeffs + float4 stream --------------
__global__ __launch_bounds__(256) void k_bnnorm(
    float* __restrict__ out, const float* __restrict__ bn8,
    const float* __restrict__ gamma, const float* __restrict__ beta, int N)
{
    __shared__ float a_s[128], c_s[128];
    int tid = threadIdx.x;
    if (tid < 128) {
        float s = 0.f, s2 = 0.f;
#pragma unroll
        for (int b = 0; b < 8; ++b) {
            s  += bn8[b * 256 + tid];
            s2 += bn8[b * 256 + 128 + tid];
        }
        float invN = 1.f / (float)N;
        float mean = s * invN;
        float var = s2 * invN - mean * mean;
        float a = rsqrtf(var + 1e-5f) * gamma[tid];
        a_s[tid] = a;
        c_s[tid] = beta[tid] - mean * a;
    }
    __syncthreads();
    int idx = blockIdx.x * 256 + tid;          // float4 index
    int total = N * 32;                        // N*128/4
    if (idx >= total) return;
    float4 x = ((const float4*)out)[idx];
    int d0 = (idx * 4) & 127;
    x.x = x.x * a_s[d0]     + c_s[d0];
    x.y = x.y * a_s[d0 + 1] + c_s[d0 + 1];
    x.z = x.z * a_s[d0 + 2] + c_s[d0 + 2];
    x.w = x.w * a_s[d0 + 3] + c_s[d0 + 3];
    ((float4*)out)[idx] = x;
}

// ---- host launcher -------------------------------------------------------
extern "C" void kernel_launch(void* const* d_in, const int* in_sizes, int n_in,
                              void* d_out, int out_size, void* d_ws, size_t ws_size,
                              hipStream_t stream)
{
    const float* nf     = (const float*)d_in[0];
    const int*   src    = (const int*)  d_in[1];
    const int*   dst    = (const int*)  d_in[2];
    const float* W_edge = (const float*)d_in[3];
    const float* b_edge = (const float*)d_in[4];
    const float* W_proj = (const float*)d_in[5];
    const float* b_proj = (const float*)d_in[6];
    const float* W_ih   = (const float*)d_in[7];
    const float* W_hh   = (const float*)d_in[8];
    const float* b_ih   = (const float*)d_in[9];
    const float* b_hh   = (const float*)d_in[10];
    const float* bn_g   = (const float*)d_in[11];
    const float* bn_b   = (const float*)d_in[12];

    const int N   = in_sizes[0] / D;   // 50000 (must be <= 65536 for 16-bit src)
    const int E   = in_sizes[1];       // 600000
    const int NBK = (N + 255) >> 8;    // 196 buckets

    float* ws = (float*)d_ws;
    float* s_d        = ws;                                 // N
    float* s_s        = ws + (size_t)N;                     // N
    float* den        = ws + (size_t)2 * N;                 // N
    int*   row_start  = (int*)(ws + (size_t)3 * N);         // N
    int*   row_cnt    = (int*)(ws + (size_t)4 * N);         // N
    int*   gcur       = (int*)(ws + (size_t)5 * N);         // 256
    float* bn8        = ws + (size_t)5 * N + 256;           // 2048
    uint_t* pre_rec   = (uint_t*)(ws + (size_t)5 * N + 2304);            // NBK*BCAP
    uint2*  edge_rec  = (uint2*)(pre_rec + (size_t)NBK * BCAP);          // NBK*BCAP*8B
    ushort_t* nf16    = (ushort_t*)(edge_rec + (size_t)NBK * BCAP);
    ushort_t* hv16    = nf16 + (size_t)N * 128;
    ushort_t* ctx16   = hv16 + (size_t)N * 128;
    ushort_t* Wih16   = ctx16 + (size_t)N * 128;
    ushort_t* Whh16   = Wih16 + 384 * 128;
    ushort_t* WpT16   = Whh16 + 384 * 128;

    float* outp = (float*)d_out;

    int nb_part = (E + 256 * EPT - 1) / (256 * EPT);   // 147
    int nb_hv   = (N + 63) / 64;                       // 782

    k_prep_w<<<(114688 + 2304 + 255) / 256, 256, 0, stream>>>(
        W_ih, W_hh, W_proj, Wih16, Whh16, WpT16, gcur, bn8, NBK);
    k_hv_part<<<nb_part + nb_hv, 256, 0, stream>>>(
        nf, WpT16, b_proj, W_edge, nf16, hv16, s_d, s_s,
        src, dst, gcur, pre_rec, N, NBK, E, nb_part);
    k_bucket<<<NBK, 256, 0, stream>>>(pre_rec, gcur, s_d, s_s, b_edge,
                                      row_start, row_cnt, edge_rec, den, N);
    k_agg4<<<(N + 7) / 8, 256, 0, stream>>>(hv16, row_start, row_cnt, den,
                                            edge_rec, ctx16, N);
    k_gru_mfma<<<dim3(128, 2), 1024, 0, stream>>>(ctx16, nf16, Wih16, Whh16,
                                                  b_ih, b_hh, outp, bn8, N);
    k_bnnorm<<<(N * 32 + 255) / 256, 256, 0, stream>>>(outp, bn8, bn_g, bn_b, N);
}